// Round 25
// baseline (118.268 us; speedup 1.0000x reference)
//
#include <hip/hip_runtime.h>
#include <cstddef>

#define HIDDEN 768
#define NHEADS 12
#define HDIM   64
#define BATCH  2
#define SEQ    2048
#define NROWS  (BATCH*SEQ)   // 4096
#define LOG2E  1.4426950408889634f

typedef float f32x4  __attribute__((ext_vector_type(4)));
typedef float f32x16 __attribute__((ext_vector_type(16)));
typedef short bf16x8 __attribute__((ext_vector_type(8)));

__device__ __forceinline__ float fast_exp2(float x){   // v_exp_f32: D = 2^S0
    return __builtin_amdgcn_exp2f(x);
}

__device__ __forceinline__ unsigned short f2bf(float f){   // RNE (prep paths)
    unsigned u = __builtin_bit_cast(unsigned, f);
    u = u + 0x7FFFu + ((u >> 16) & 1u);
    return (unsigned short)(u >> 16);
}
__device__ __forceinline__ unsigned packbf2(float a, float b){ // (lo=a, hi=b), half-up
    unsigned ua = (__builtin_bit_cast(unsigned, a) + 0x8000u) >> 16;
    unsigned ub = (__builtin_bit_cast(unsigned, b) + 0x8000u) & 0xFFFF0000u;
    return ua | ub;
}
__device__ __forceinline__ unsigned cvtpk_bf16(float a, float b){ // HW pack (T12)
    unsigned r;
    asm("v_cvt_pk_bf16_f32 %0, %1, %2" : "=v"(r) : "v"(a), "v"(b));
    return r;
}

// async global->LDS, 16B per lane; lds base wave-uniform (lane i -> base+i*16)
__device__ __forceinline__ void gl_lds16(const unsigned short* g, unsigned short* l){
    __builtin_amdgcn_global_load_lds(
        (const __attribute__((address_space(1))) unsigned int*)g,
        (__attribute__((address_space(3))) unsigned int*)l, 16, 0, 0);
}

// ---------------------------------------------------------------------------
// Elementwise fp32 -> bf16
// ---------------------------------------------------------------------------
__global__ __launch_bounds__(256) void cvt_bf16(const float* __restrict__ in,
                                                unsigned short* __restrict__ out,
                                                int n4)
{
    const int i = blockIdx.x * 256 + threadIdx.x;
    if (i >= n4) return;
    const float4 v = reinterpret_cast<const float4*>(in)[i];
    ushort4 o;
    o.x = f2bf(v.x); o.y = f2bf(v.y); o.z = f2bf(v.z); o.w = f2bf(v.w);
    reinterpret_cast<ushort4*>(out)[i] = o;
}

// ---------------------------------------------------------------------------
// All four 768x768 fp32 W -> bf16 W^T in one launch (z = which matrix)
// ---------------------------------------------------------------------------
__global__ __launch_bounds__(256) void transpose_cvt4(const float* __restrict__ W0,
                                                      const float* __restrict__ W1,
                                                      const float* __restrict__ W2,
                                                      const float* __restrict__ W3,
                                                      unsigned short* __restrict__ T0,
                                                      unsigned short* __restrict__ T1,
                                                      unsigned short* __restrict__ T2,
                                                      unsigned short* __restrict__ T3)
{
    const int z = blockIdx.z;
    const float* W = (z == 0) ? W0 : (z == 1) ? W1 : (z == 2) ? W2 : W3;
    unsigned short* Wt = (z == 0) ? T0 : (z == 1) ? T1 : (z == 2) ? T2 : T3;

    __shared__ unsigned short t[64][66];
    const int k0 = blockIdx.y * 64, n0 = blockIdx.x * 64;
    const int row = threadIdx.x >> 2;
    const int c0  = (threadIdx.x & 3) * 16;
#pragma unroll
    for (int j = 0; j < 16; j += 4) {
        const float4 v = *reinterpret_cast<const float4*>(&W[(size_t)(k0 + row) * HIDDEN + n0 + c0 + j]);
        t[row][c0 + j + 0] = f2bf(v.x);
        t[row][c0 + j + 1] = f2bf(v.y);
        t[row][c0 + j + 2] = f2bf(v.z);
        t[row][c0 + j + 3] = f2bf(v.w);
    }
    __syncthreads();
#pragma unroll
    for (int j = 0; j < 16; j += 4) {
        ushort4 o;
        o.x = t[c0 + j + 0][row];
        o.y = t[c0 + j + 1][row];
        o.z = t[c0 + j + 2][row];
        o.w = t[c0 + j + 3][row];
        *reinterpret_cast<ushort4*>(&Wt[(size_t)(n0 + row) * HIDDEN + k0 + c0 + j]) = o;
    }
}

// ---------------------------------------------------------------------------
// GEMM core: 64x96 tile, BK=64, 2-phase ping-pong staging (T3-minimum).
// STAGE(next buf) issued BEFORE compute(current buf); one barrier per k-step
// whose vmcnt drain lands AFTER a full compute phase of overlap.
// Barrier audit: every buffer has a barrier between its last read and its
// re-stage, and between its stage and its first read.
// ---------------------------------------------------------------------------
#define G_STAGE(buf, k0) do {                                                                  \
    unsigned short* Ad = As + (buf) * 4096;                                                    \
    unsigned short* Bd = Bs + (buf) * 6144;                                                    \
    _Pragma("unroll")                                                                          \
    for (int a_ = 0; a_ < 2; ++a_) {                                                           \
        const int row_ = (a_ * 4 + w) * 8 + srow;                                              \
        const int sl_ = sslot ^ (row_ & 7);                                                    \
        gl_lds16(&A[(size_t)(m0 + row_) * HIDDEN + (k0) + sl_ * 8], &Ad[(a_ * 4 + w) * 512]);  \
    }                                                                                          \
    _Pragma("unroll")                                                                          \
    for (int b_ = 0; b_ < 3; ++b_) {                                                           \
        const int row_ = (b_ * 4 + w) * 8 + srow;                                              \
        const int sl_ = sslot ^ (row_ & 7);                                                    \
        gl_lds16(&Wt[(size_t)(n0 + row_) * HIDDEN + (k0) + sl_ * 8], &Bd[(b_ * 4 + w) * 512]); \
    }                                                                                          \
} while (0)

#define G_COMPUTE(buf) do {                                                                    \
    unsigned short* Ad = As + (buf) * 4096;                                                    \
    unsigned short* Bd = Bs + (buf) * 6144;                                                    \
    _Pragma("unroll")                                                                          \
    for (int kk = 0; kk < 2; ++kk) {                                                           \
        bf16x8 af[2], bfr[3];                                                                  \
        _Pragma("unroll")                                                                      \
        for (int mi = 0; mi < 2; ++mi) {                                                       \
            const int r_ = wm * 32 + mi * 16 + l15;                                            \
            af[mi] = *reinterpret_cast<const bf16x8*>(&Ad[r_ * 64 + ((lg * 8 + kk * 32) ^ ((r_ & 7) << 3))]); \
        }                                                                                      \
        _Pragma("unroll")                                                                      \
        for (int ni = 0; ni < 3; ++ni) {                                                       \
            const int r_ = wn * 48 + ni * 16 + l15;                                            \
            bfr[ni] = *reinterpret_cast<const bf16x8*>(&Bd[r_ * 64 + ((lg * 8 + kk * 32) ^ ((r_ & 7) << 3))]); \
        }                                                                                      \
        _Pragma("unroll")                                                                      \
        for (int mi = 0; mi < 2; ++mi)                                                         \
            _Pragma("unroll")                                                                  \
            for (int ni = 0; ni < 3; ++ni)                                                     \
                acc[mi][ni] = __builtin_amdgcn_mfma_f32_16x16x32_bf16(af[mi], bfr[ni], acc[mi][ni], 0, 0, 0); \
    }                                                                                          \
} while (0)

__device__ __forceinline__ void gemm_body(const unsigned short* __restrict__ A,
                                          const unsigned short* __restrict__ Wt,
                                          const float* __restrict__ bias,
                                          void* __restrict__ Cout, int mode,
                                          float scale,
                                          unsigned short* As, unsigned short* Bs)
{
    const int tid = threadIdx.x;
    const int l = tid & 63, w = tid >> 6;
    const int wm = w >> 1, wn = w & 1;
    const int l15 = l & 15, lg = l >> 4;
    const int srow = l >> 3, sslot = l & 7;
    const int m0 = blockIdx.y * 64, n0 = blockIdx.x * 96;

    f32x4 acc[2][3] = {};

    G_STAGE(0, 0);
    __syncthreads();                       // buf0 landed (vmcnt drained by compiler)
#pragma unroll
    for (int i = 0; i < 6; ++i) {          // 12 k-steps, ping-pong
        G_STAGE(1, (2 * i + 1) * 64);      // issue buf1 loads
        G_COMPUTE(0);                      // compute on buf0 (overlap)
        __syncthreads();                   // buf1 landed; all reads of buf0 done
        if (i < 5) G_STAGE(0, (2 * i + 2) * 64);
        G_COMPUTE(1);
        __syncthreads();                   // buf0 landed; all reads of buf1 done
    }

#pragma unroll
    for (int mi = 0; mi < 2; ++mi) {
#pragma unroll
        for (int ni = 0; ni < 3; ++ni) {
#pragma unroll
            for (int rr = 0; rr < 4; ++rr) {
                const int row = m0 + wm * 32 + mi * 16 + lg * 4 + rr;
                const int col = n0 + wn * 48 + ni * 16 + l15;
                const float v = (acc[mi][ni][rr] + bias[col]) * scale;
                if (mode == 0) {
                    const int b = row >> 11, s = row & (SEQ - 1);
                    const int hh = col >> 6, d = col & (HDIM - 1);
                    ((unsigned short*)Cout)[(((size_t)b * NHEADS + hh) * SEQ + s) * HDIM + d] = f2bf(v);
                } else if (mode == 1) {
                    const int b = row >> 11, s = row & (SEQ - 1);
                    const int hh = col >> 6, d = col & (HDIM - 1);
                    ((unsigned short*)Cout)[(((size_t)b * NHEADS + hh) * HDIM + d) * SEQ + s] = f2bf(v);
                } else {
                    ((float*)Cout)[(size_t)row * HIDDEN + col] = v;
                }
            }
        }
    }
}

// Fused Q/K/V projection: blockIdx.z selects weight/bias/output/mode/scale.
__global__ __launch_bounds__(256) void qkv_gemm(const unsigned short* __restrict__ A,
                                                const unsigned short* __restrict__ Wqt,
                                                const unsigned short* __restrict__ Wkt,
                                                const unsigned short* __restrict__ Wvt,
                                                const float* __restrict__ bq,
                                                const float* __restrict__ bk,
                                                const float* __restrict__ bv,
                                                unsigned short* __restrict__ Qb,
                                                unsigned short* __restrict__ Kb,
                                                unsigned short* __restrict__ Vtb)
{
    __shared__ unsigned short As[2 * 4096];
    __shared__ unsigned short Bs[2 * 6144];
    const int z = blockIdx.z;
    const unsigned short* Wt = (z == 0) ? Wqt : (z == 1) ? Wkt : Wvt;
    const float* bias = (z == 0) ? bq : (z == 1) ? bk : bv;
    void* out = (z == 0) ? (void*)Qb : (z == 1) ? (void*)Kb : (void*)Vtb;
    const int mode = (z == 2) ? 1 : 0;
    const float scale = (z == 0) ? LOG2E : 1.0f;
    gemm_body(A, Wt, bias, out, mode, scale, As, Bs);
}

// Output projection (fp32 out).
__global__ __launch_bounds__(256) void out_gemm(const unsigned short* __restrict__ A,
                                                const unsigned short* __restrict__ Wt,
                                                const float* __restrict__ bias,
                                                float* __restrict__ Cout)
{
    __shared__ unsigned short As[2 * 4096];
    __shared__ unsigned short Bs[2 * 6144];
    gemm_body(A, Wt, bias, Cout, 2, 1.0f, As, Bs);
}

// ---------------------------------------------------------------------------
// Flash attention — EXACT round-24 kernel (best measured: attn ~60 us,
// both validations passed). Swapped-QK^T 32x32 MFMA, exp2-domain, defer-max,
// kv-split, cvt_pk P-pack (T12), permlane32_swap B-frag exchange.
// ---------------------------------------------------------------------------
__global__ __launch_bounds__(256) void attn_mfma(const unsigned short* __restrict__ Q,
                                                 const unsigned short* __restrict__ K,
                                                 const unsigned short* __restrict__ Vt,
                                                 unsigned short* __restrict__ O)
{
    // [0,16384): Ks[2][4096]  /  reused as xch[2][2048] f32 in combine
    // [16384,32768): Vs[2][4096]  /  reused as Ep[2][32][33] uint in epilogue
    // [32768,+1024): ml float2[2][2][32]
    __shared__ __align__(16) char shraw[33792];
    unsigned short* Ks  = (unsigned short*)shraw;            // [wkv][4096]
    unsigned short* Vs  = (unsigned short*)(shraw + 16384);  // [wkv][4096]
    float*          xch = (float*)shraw;                     // [wq2][2048]
    unsigned int*   Ep  = (unsigned int*)(shraw + 16384);    // [wq2][32][33]
    float2*         mlx = (float2*)(shraw + 32768);          // [wq2][wkv][32]

    const int tid = threadIdx.x;
    const int l = tid & 63;
    const int wq2 = (tid >> 6) & 1;          // q sub-block
    const int wkv = tid >> 7;                // kv split
    const int l31 = l & 31, hi = l >> 5;
    const int lr = l >> 3, slot = l & 7;     // staging lane decomposition
    const int q0 = blockIdx.x * 64;
    const int h = blockIdx.y, b = blockIdx.z;
    const size_t base = ((size_t)b * NHEADS + h) * (size_t)SEQ * HDIM;

    // Q fragments (B-operand): col q = l&31, k(d) = 16t + 8hi + i
    const int q = q0 + wq2 * 32 + l31;
    bf16x8 qf[4];
#pragma unroll
    for (int t = 0; t < 4; ++t)
        qf[t] = *reinterpret_cast<const bf16x8*>(&Q[base + (size_t)q * HDIM + 16 * t + 8 * hi]);

    f32x16 accO[2] = {};      // O^T partial: rows d = 32*db + crow(r,hi), col q = l31
    float m = -1e30f, lsum = 0.f;

    unsigned short* Kb = Ks + wkv * 4096;
    unsigned short* Vb = Vs + wkv * 4096;
    const int kvbase = wkv * (SEQ / 2);

    for (int i = 0; i < SEQ / 128; ++i) {
        const int t0 = kvbase + i * 64;
        __syncthreads();                 // all waves done reading prev tiles
#pragma unroll
        for (int j = 0; j < 4; ++j) {    // pair (wq2=0,1) covers 64 rows of K and Vt
            const int row = (j * 2 + wq2) * 8 + lr;
            const int sl = slot ^ (row & 7);
            gl_lds16(&K [base + (size_t)(t0 + row) * HDIM + sl * 8], &Kb[(j * 2 + wq2) * 512]);
            gl_lds16(&Vt[base + (size_t)row * SEQ + t0 + sl * 8],    &Vb[(j * 2 + wq2) * 512]);
        }
        __syncthreads();                 // vmcnt drained by compiler before barrier

        // S^T tiles: s0v = kv 0-31, s1v = kv 32-63 of this tile
        f32x16 s0v = {}, s1v = {};
        __builtin_amdgcn_s_setprio(1);
#pragma unroll
        for (int t = 0; t < 4; ++t) {
            const int co = 16 * t + 8 * hi;
            const int r0 = l31, r1 = 32 + l31;
            const bf16x8 k0 = *reinterpret_cast<const bf16x8*>(&Kb[r0 * 64 + (co ^ ((r0 & 7) << 3))]);
            const bf16x8 k1 = *reinterpret_cast<const bf16x8*>(&Kb[r1 * 64 + (co ^ ((r1 & 7) << 3))]);
            s0v = __builtin_amdgcn_mfma_f32_32x32x16_bf16(k0, qf[t], s0v, 0, 0, 0);
            s1v = __builtin_amdgcn_mfma_f32_32x32x16_bf16(k1, qf[t], s1v, 0, 0, 0);
        }
        __builtin_amdgcn_s_setprio(0);

        // max tree (4-wide groups -> v_max3 fusion) + cross-half combine
        float tmax = -1e30f;
#pragma unroll
        for (int r = 0; r < 16; r += 4) {
            tmax = fmaxf(tmax, fmaxf(fmaxf(s0v[r], s0v[r + 1]), fmaxf(s0v[r + 2], s0v[r + 3])));
            tmax = fmaxf(tmax, fmaxf(fmaxf(s1v[r], s1v[r + 1]), fmaxf(s1v[r + 2], s1v[r + 3])));
        }
        tmax = fmaxf(tmax, __shfl_xor(tmax, 32));

        // defer-max (T13): rescale only when tile max grows > 8 (exp2 domain)
        if (tmax > m + 8.f) {
            const float scl = fast_exp2(m - tmax);
            lsum *= scl;
#pragma unroll
            for (int r = 0; r < 16; ++r) { accO[0][r] *= scl; accO[1][r] *= scl; }
            m = tmax;
        }

        // fused exp -> HW bf16 pack (v_cvt_pk_bf16_f32: 1 instr/pair)
        unsigned wv[16];
        float ls = 0.f;
#pragma unroll
        for (int a = 0; a < 8; ++a) {
            const float pa = fast_exp2(s0v[2 * a] - m);
            const float pb = fast_exp2(s0v[2 * a + 1] - m);
            ls += pa + pb;
            wv[a] = cvtpk_bf16(pa, pb);
        }
#pragma unroll
        for (int a = 0; a < 8; ++a) {
            const float pa = fast_exp2(s1v[2 * a] - m);
            const float pb = fast_exp2(s1v[2 * a + 1] - m);
            ls += pa + pb;
            wv[8 + a] = cvtpk_bf16(pa, pb);
        }
        ls += __shfl_xor(ls, 32);
        lsum += ls;

        // PV: per k-slot, B-frag via v_permlane32_swap (2 ops replace 4 shfl+4 sel)
#pragma unroll
        for (int slot2 = 0; slot2 < 4; ++slot2) {
            unsigned a0 = wv[slot2 * 4 + 0], a2 = wv[slot2 * 4 + 2];
            unsigned a1 = wv[slot2 * 4 + 1], a3 = wv[slot2 * 4 + 3];
            asm volatile("v_permlane32_swap_b32 %0, %1" : "+v"(a0), "+v"(a2));
            asm volatile("v_permlane32_swap_b32 %0, %1" : "+v"(a1), "+v"(a3));
            uint4 fr;
            fr.x = a0;   // == hi ? x2 : w0
            fr.y = a1;   // == hi ? x3 : w1
            fr.z = a2;   // == hi ? w2 : x0
            fr.w = a3;   // == hi ? w3 : x1
            const bf16x8 pfrag = __builtin_bit_cast(bf16x8, fr);
            __builtin_amdgcn_s_setprio(1);
#pragma unroll
            for (int db = 0; db < 2; ++db) {
                const int vr = 32 * db + l31;
                const int co = (16 * slot2 + 8 * hi) ^ ((vr & 7) << 3);
                const bf16x8 vf = *reinterpret_cast<const bf16x8*>(&Vb[vr * 64 + co]);
                accO[db] = __builtin_amdgcn_mfma_f32_32x32x16_bf16(vf, pfrag, accO[db], 0, 0, 0);
            }
            __builtin_amdgcn_s_setprio(0);
        }
    }

    // ---- flash merge of the two kv-split partials ----
    __syncthreads();                     // loop LDS use complete
    if (!hi) mlx[(wq2 * 2 + wkv) * 32 + l31] = make_float2(m, lsum);
    __syncthreads();
    const float2 mp = mlx[(wq2 * 2 + (1 - wkv)) * 32 + l31];
    const float M  = fmaxf(m, mp.x);
    const float s  = fast_exp2(m - M);
    const float lf = lsum * s + mp.y * fast_exp2(mp.x - M);

    if (wkv == 1) {                      // publish scaled partial (overlays Ks region)
#pragma unroll
        for (int db = 0; db < 2; ++db)
#pragma unroll
            for (int r = 0; r < 16; ++r) {
                const int d = 32 * db + (r & 3) + 8 * (r >> 2) + 4 * hi;
                xch[wq2 * 2048 + d * 32 + l31] = accO[db][r] * s;
            }
    }
    __syncthreads();
    if (wkv == 0) {                      // merge + normalize + Ep transpose
        const float inv = 1.f / lf;
#pragma unroll
        for (int db = 0; db < 2; ++db)
#pragma unroll
            for (int r = 0; r < 16; ++r) {
                const int d = 32 * db + (r & 3) + 8 * (r >> 2) + 4 * hi;
                accO[db][r] = (accO[db][r] * s + xch[wq2 * 2048 + d * 32 + l31]) * inv;
            }
#pragma unroll
        for (int db = 0; db < 2; ++db)
#pragma unroll
            for (int a = 0; a < 8; ++a) {
                const unsigned wd = packbf2(accO[db][2 * a], accO[db][2 * a + 1]);
                const int pi = 16 * db + 4 * (a >> 1) + (a & 1) + 2 * hi;  // d-pair index
                Ep[(wq2 * 32 + l31) * 33 + pi] = wd;
            }
    }
    __syncthreads();                     // fence Ep writes -> reads
    if (wkv == 0) {
#pragma unroll
        for (int pss = 0; pss < 4; ++pss) {
            const int idx = pss * 64 + l;
            const int qr = idx >> 3, c = idx & 7;
            uint4 ov;
            ov.x = Ep[(wq2 * 32 + qr) * 33 + c * 4 + 0];
            ov.y = Ep[(wq2 * 32 + qr) * 33 + c * 4 + 1];
            ov.z = Ep[(wq2 * 32 + qr) * 33 + c * 4 + 2];
            ov.w = Ep[(wq2 * 32 + qr) * 33 + c * 4 + 3];
            *reinterpret_cast<uint4*>(&O[((size_t)b * SEQ + q0 + wq2 * 32 + qr) * HIDDEN + h * HDIM + c * 8]) = ov;
        }
    }
}

// ---------------------------------------------------------------------------
extern "C" void kernel_launch(void* const* d_in, const int* in_sizes, int n_in,
                              void* d_out, int out_size, void* d_ws, size_t ws_size,
                              hipStream_t stream)
{
    const float* x  = (const float*)d_in[0];
    const float* Wq = (const float*)d_in[1];
    const float* bq = (const float*)d_in[2];
    const float* Wk = (const float*)d_in[3];
    const float* bk = (const float*)d_in[4];
    const float* Wv = (const float*)d_in[5];
    const float* bv = (const float*)d_in[6];
    const float* Wo = (const float*)d_in[7];
    const float* bo = (const float*)d_in[8];
    float* out = (float*)d_out;

    unsigned short* p = (unsigned short*)d_ws;
    const size_t szX = (size_t)NROWS * HIDDEN;
    const size_t szW = (size_t)HIDDEN * HIDDEN;
    const size_t szH = (size_t)BATCH * NHEADS * SEQ * HDIM;
    unsigned short* xb  = p;              p += szX;
    unsigned short* Wqt = p;              p += szW;
    unsigned short* Wkt = p;              p += szW;
    unsigned short* Wvt = p;              p += szW;
    unsigned short* Wot = p;              p += szW;
    unsigned short* Qb  = p;              p += szH;
    unsigned short* Kb  = p;              p += szH;
    unsigned short* Vtb = p;              p += szH;
    unsigned short* Oab = p;              p += szX;

    cvt_bf16<<<(int)(szX / 4 + 255) / 256, 256, 0, stream>>>(x, xb, (int)(szX / 4));
    transpose_cvt4<<<dim3(HIDDEN / 64, HIDDEN / 64, 4), 256, 0, stream>>>(
        Wq, Wk, Wv, Wo, Wqt, Wkt, Wvt, Wot);

    qkv_gemm<<<dim3(HIDDEN / 96, NROWS / 64, 3), 256, 0, stream>>>(
        xb, Wqt, Wkt, Wvt, bq, bk, bv, Qb, Kb, Vtb);

    attn_mfma<<<dim3(SEQ / 64, NHEADS, BATCH), 256, 0, stream>>>(Qb, Kb, Vtb, Oab);

    out_gemm<<<dim3(HIDDEN / 96, NROWS / 64), 256, 0, stream>>>(Oab, Wot, bo, out);
}

// Round 26
// 109.724 us; speedup vs baseline: 1.0779x; 1.0779x over previous
//
#include <hip/hip_runtime.h>
#include <cstddef>

#define HIDDEN 768
#define NHEADS 12
#define HDIM   64
#define BATCH  2
#define SEQ    2048
#define NROWS  (BATCH*SEQ)   // 4096
#define LOG2E  1.4426950408889634f

typedef float f32x4  __attribute__((ext_vector_type(4)));
typedef float f32x16 __attribute__((ext_vector_type(16)));
typedef short bf16x8 __attribute__((ext_vector_type(8)));

__device__ __forceinline__ float fast_exp2(float x){   // v_exp_f32: D = 2^S0
    return __builtin_amdgcn_exp2f(x);
}

__device__ __forceinline__ unsigned short f2bf(float f){   // RNE (prep paths)
    unsigned u = __builtin_bit_cast(unsigned, f);
    u = u + 0x7FFFu + ((u >> 16) & 1u);
    return (unsigned short)(u >> 16);
}
__device__ __forceinline__ unsigned packbf2(float a, float b){ // (lo=a, hi=b), half-up
    unsigned ua = (__builtin_bit_cast(unsigned, a) + 0x8000u) >> 16;
    unsigned ub = (__builtin_bit_cast(unsigned, b) + 0x8000u) & 0xFFFF0000u;
    return ua | ub;
}
__device__ __forceinline__ unsigned cvtpk_bf16(float a, float b){ // HW pack (T12)
    unsigned r;
    asm("v_cvt_pk_bf16_f32 %0, %1, %2" : "=v"(r) : "v"(a), "v"(b));
    return r;
}

// async global->LDS, 16B per lane; lds base wave-uniform (lane i -> base+i*16)
__device__ __forceinline__ void gl_lds16(const unsigned short* g, unsigned short* l){
    __builtin_amdgcn_global_load_lds(
        (const __attribute__((address_space(1))) unsigned int*)g,
        (__attribute__((address_space(3))) unsigned int*)l, 16, 0, 0);
}

// ---------------------------------------------------------------------------
// Elementwise fp32 -> bf16
// ---------------------------------------------------------------------------
__global__ __launch_bounds__(256) void cvt_bf16(const float* __restrict__ in,
                                                unsigned short* __restrict__ out,
                                                int n4)
{
    const int i = blockIdx.x * 256 + threadIdx.x;
    if (i >= n4) return;
    const float4 v = reinterpret_cast<const float4*>(in)[i];
    ushort4 o;
    o.x = f2bf(v.x); o.y = f2bf(v.y); o.z = f2bf(v.z); o.w = f2bf(v.w);
    reinterpret_cast<ushort4*>(out)[i] = o;
}

// ---------------------------------------------------------------------------
// All four 768x768 fp32 W -> bf16 W^T in one launch (z = which matrix)
// ---------------------------------------------------------------------------
__global__ __launch_bounds__(256) void transpose_cvt4(const float* __restrict__ W0,
                                                      const float* __restrict__ W1,
                                                      const float* __restrict__ W2,
                                                      const float* __restrict__ W3,
                                                      unsigned short* __restrict__ T0,
                                                      unsigned short* __restrict__ T1,
                                                      unsigned short* __restrict__ T2,
                                                      unsigned short* __restrict__ T3)
{
    const int z = blockIdx.z;
    const float* W = (z == 0) ? W0 : (z == 1) ? W1 : (z == 2) ? W2 : W3;
    unsigned short* Wt = (z == 0) ? T0 : (z == 1) ? T1 : (z == 2) ? T2 : T3;

    __shared__ unsigned short t[64][66];
    const int k0 = blockIdx.y * 64, n0 = blockIdx.x * 64;
    const int row = threadIdx.x >> 2;
    const int c0  = (threadIdx.x & 3) * 16;
#pragma unroll
    for (int j = 0; j < 16; j += 4) {
        const float4 v = *reinterpret_cast<const float4*>(&W[(size_t)(k0 + row) * HIDDEN + n0 + c0 + j]);
        t[row][c0 + j + 0] = f2bf(v.x);
        t[row][c0 + j + 1] = f2bf(v.y);
        t[row][c0 + j + 2] = f2bf(v.z);
        t[row][c0 + j + 3] = f2bf(v.w);
    }
    __syncthreads();
#pragma unroll
    for (int j = 0; j < 16; j += 4) {
        ushort4 o;
        o.x = t[c0 + j + 0][row];
        o.y = t[c0 + j + 1][row];
        o.z = t[c0 + j + 2][row];
        o.w = t[c0 + j + 3][row];
        *reinterpret_cast<ushort4*>(&Wt[(size_t)(n0 + row) * HIDDEN + k0 + c0 + j]) = o;
    }
}

// ---------------------------------------------------------------------------
// GEMM core (64x96 tile, BK=64, gl_lds staging, XOR-swizzled LDS) as a
// device function; mode 0: bf16 [B,H,S,D]; 1: bf16 [B,H,D,S]; 2: fp32 rowmaj.
// Single-buffered (r13-proven): at K=768 / 6 blocks/CU this beats ping-pong.
// ---------------------------------------------------------------------------
__device__ __forceinline__ void gemm_body(const unsigned short* __restrict__ A,
                                          const unsigned short* __restrict__ Wt,
                                          const float* __restrict__ bias,
                                          void* __restrict__ Cout, int mode,
                                          float scale,
                                          unsigned short* As, unsigned short* Bs)
{
    const int tid = threadIdx.x;
    const int l = tid & 63, w = tid >> 6;
    const int wm = w >> 1, wn = w & 1;
    const int l15 = l & 15, lg = l >> 4;
    const int srow = l >> 3, sslot = l & 7;
    const int m0 = blockIdx.y * 64, n0 = blockIdx.x * 96;

    f32x4 acc[2][3] = {};

    for (int k0 = 0; k0 < HIDDEN; k0 += 64) {
        __syncthreads();
#pragma unroll
        for (int a = 0; a < 2; ++a) {
            const int row = (a * 4 + w) * 8 + srow;
            const int sl = sslot ^ (row & 7);
            gl_lds16(&A[(size_t)(m0 + row) * HIDDEN + k0 + sl * 8], &As[(a * 4 + w) * 512]);
        }
#pragma unroll
        for (int b = 0; b < 3; ++b) {
            const int row = (b * 4 + w) * 8 + srow;
            const int sl = sslot ^ (row & 7);
            gl_lds16(&Wt[(size_t)(n0 + row) * HIDDEN + k0 + sl * 8], &Bs[(b * 4 + w) * 512]);
        }
        __syncthreads();

#pragma unroll
        for (int kk = 0; kk < 2; ++kk) {
            bf16x8 af[2], bfr[3];
#pragma unroll
            for (int mi = 0; mi < 2; ++mi) {
                const int r = wm * 32 + mi * 16 + l15;
                af[mi] = *reinterpret_cast<const bf16x8*>(&As[r * 64 + ((lg * 8 + kk * 32) ^ ((r & 7) << 3))]);
            }
#pragma unroll
            for (int ni = 0; ni < 3; ++ni) {
                const int r = wn * 48 + ni * 16 + l15;
                bfr[ni] = *reinterpret_cast<const bf16x8*>(&Bs[r * 64 + ((lg * 8 + kk * 32) ^ ((r & 7) << 3))]);
            }
#pragma unroll
            for (int mi = 0; mi < 2; ++mi)
#pragma unroll
                for (int ni = 0; ni < 3; ++ni)
                    acc[mi][ni] = __builtin_amdgcn_mfma_f32_16x16x32_bf16(af[mi], bfr[ni], acc[mi][ni], 0, 0, 0);
        }
    }

#pragma unroll
    for (int mi = 0; mi < 2; ++mi) {
#pragma unroll
        for (int ni = 0; ni < 3; ++ni) {
#pragma unroll
            for (int rr = 0; rr < 4; ++rr) {
                const int row = m0 + wm * 32 + mi * 16 + lg * 4 + rr;
                const int col = n0 + wn * 48 + ni * 16 + l15;
                const float v = (acc[mi][ni][rr] + bias[col]) * scale;
                if (mode == 0) {
                    const int b = row >> 11, s = row & (SEQ - 1);
                    const int hh = col >> 6, d = col & (HDIM - 1);
                    ((unsigned short*)Cout)[(((size_t)b * NHEADS + hh) * SEQ + s) * HDIM + d] = f2bf(v);
                } else if (mode == 1) {
                    const int b = row >> 11, s = row & (SEQ - 1);
                    const int hh = col >> 6, d = col & (HDIM - 1);
                    ((unsigned short*)Cout)[(((size_t)b * NHEADS + hh) * HDIM + d) * SEQ + s] = f2bf(v);
                } else {
                    ((float*)Cout)[(size_t)row * HIDDEN + col] = v;
                }
            }
        }
    }
}

// Fused Q/K/V projection: blockIdx.z selects weight/bias/output/mode/scale.
__global__ __launch_bounds__(256) void qkv_gemm(const unsigned short* __restrict__ A,
                                                const unsigned short* __restrict__ Wqt,
                                                const unsigned short* __restrict__ Wkt,
                                                const unsigned short* __restrict__ Wvt,
                                                const float* __restrict__ bq,
                                                const float* __restrict__ bk,
                                                const float* __restrict__ bv,
                                                unsigned short* __restrict__ Qb,
                                                unsigned short* __restrict__ Kb,
                                                unsigned short* __restrict__ Vtb)
{
    __shared__ unsigned short As[64 * 64];
    __shared__ unsigned short Bs[96 * 64];
    const int z = blockIdx.z;
    const unsigned short* Wt = (z == 0) ? Wqt : (z == 1) ? Wkt : Wvt;
    const float* bias = (z == 0) ? bq : (z == 1) ? bk : bv;
    void* out = (z == 0) ? (void*)Qb : (z == 1) ? (void*)Kb : (void*)Vtb;
    const int mode = (z == 2) ? 1 : 0;
    const float scale = (z == 0) ? LOG2E : 1.0f;
    gemm_body(A, Wt, bias, out, mode, scale, As, Bs);
}

// Output projection (fp32 out).
__global__ __launch_bounds__(256) void out_gemm(const unsigned short* __restrict__ A,
                                                const unsigned short* __restrict__ Wt,
                                                const float* __restrict__ bias,
                                                float* __restrict__ Cout)
{
    __shared__ unsigned short As[64 * 64];
    __shared__ unsigned short Bs[96 * 64];
    gemm_body(A, Wt, bias, Cout, 2, 1.0f, As, Bs);
}

// ---------------------------------------------------------------------------
// Flash attention — EXACT round-24 kernel (measured optimum: attn ~60 us,
// total 109.9 us, both validations passed). Swapped-QK^T 32x32 MFMA,
// exp2-domain, defer-max, kv-split, cvt_pk P-pack, permlane32_swap B-frag.
// ---------------------------------------------------------------------------
__global__ __launch_bounds__(256) void attn_mfma(const unsigned short* __restrict__ Q,
                                                 const unsigned short* __restrict__ K,
                                                 const unsigned short* __restrict__ Vt,
                                                 unsigned short* __restrict__ O)
{
    // [0,16384): Ks[2][4096]  /  reused as xch[2][2048] f32 in combine
    // [16384,32768): Vs[2][4096]  /  reused as Ep[2][32][33] uint in epilogue
    // [32768,+1024): ml float2[2][2][32]
    __shared__ __align__(16) char shraw[33792];
    unsigned short* Ks  = (unsigned short*)shraw;            // [wkv][4096]
    unsigned short* Vs  = (unsigned short*)(shraw + 16384);  // [wkv][4096]
    float*          xch = (float*)shraw;                     // [wq2][2048]
    unsigned int*   Ep  = (unsigned int*)(shraw + 16384);    // [wq2][32][33]
    float2*         mlx = (float2*)(shraw + 32768);          // [wq2][wkv][32]

    const int tid = threadIdx.x;
    const int l = tid & 63;
    const int wq2 = (tid >> 6) & 1;          // q sub-block
    const int wkv = tid >> 7;                // kv split
    const int l31 = l & 31, hi = l >> 5;
    const int lr = l >> 3, slot = l & 7;     // staging lane decomposition
    const int q0 = blockIdx.x * 64;
    const int h = blockIdx.y, b = blockIdx.z;
    const size_t base = ((size_t)b * NHEADS + h) * (size_t)SEQ * HDIM;

    // Q fragments (B-operand): col q = l&31, k(d) = 16t + 8hi + i
    const int q = q0 + wq2 * 32 + l31;
    bf16x8 qf[4];
#pragma unroll
    for (int t = 0; t < 4; ++t)
        qf[t] = *reinterpret_cast<const bf16x8*>(&Q[base + (size_t)q * HDIM + 16 * t + 8 * hi]);

    f32x16 accO[2] = {};      // O^T partial: rows d = 32*db + crow(r,hi), col q = l31
    float m = -1e30f, lsum = 0.f;

    unsigned short* Kb = Ks + wkv * 4096;
    unsigned short* Vb = Vs + wkv * 4096;
    const int kvbase = wkv * (SEQ / 2);

    for (int i = 0; i < SEQ / 128; ++i) {
        const int t0 = kvbase + i * 64;
        __syncthreads();                 // all waves done reading prev tiles
#pragma unroll
        for (int j = 0; j < 4; ++j) {    // pair (wq2=0,1) covers 64 rows of K and Vt
            const int row = (j * 2 + wq2) * 8 + lr;
            const int sl = slot ^ (row & 7);
            gl_lds16(&K [base + (size_t)(t0 + row) * HDIM + sl * 8], &Kb[(j * 2 + wq2) * 512]);
            gl_lds16(&Vt[base + (size_t)row * SEQ + t0 + sl * 8],    &Vb[(j * 2 + wq2) * 512]);
        }
        __syncthreads();                 // vmcnt drained by compiler before barrier

        // S^T tiles: s0v = kv 0-31, s1v = kv 32-63 of this tile
        f32x16 s0v = {}, s1v = {};
        __builtin_amdgcn_s_setprio(1);
#pragma unroll
        for (int t = 0; t < 4; ++t) {
            const int co = 16 * t + 8 * hi;
            const int r0 = l31, r1 = 32 + l31;
            const bf16x8 k0 = *reinterpret_cast<const bf16x8*>(&Kb[r0 * 64 + (co ^ ((r0 & 7) << 3))]);
            const bf16x8 k1 = *reinterpret_cast<const bf16x8*>(&Kb[r1 * 64 + (co ^ ((r1 & 7) << 3))]);
            s0v = __builtin_amdgcn_mfma_f32_32x32x16_bf16(k0, qf[t], s0v, 0, 0, 0);
            s1v = __builtin_amdgcn_mfma_f32_32x32x16_bf16(k1, qf[t], s1v, 0, 0, 0);
        }
        __builtin_amdgcn_s_setprio(0);

        // max tree (4-wide groups -> v_max3 fusion) + cross-half combine
        float tmax = -1e30f;
#pragma unroll
        for (int r = 0; r < 16; r += 4) {
            tmax = fmaxf(tmax, fmaxf(fmaxf(s0v[r], s0v[r + 1]), fmaxf(s0v[r + 2], s0v[r + 3])));
            tmax = fmaxf(tmax, fmaxf(fmaxf(s1v[r], s1v[r + 1]), fmaxf(s1v[r + 2], s1v[r + 3])));
        }
        tmax = fmaxf(tmax, __shfl_xor(tmax, 32));

        // defer-max (T13): rescale only when tile max grows > 8 (exp2 domain)
        if (tmax > m + 8.f) {
            const float scl = fast_exp2(m - tmax);
            lsum *= scl;
#pragma unroll
            for (int r = 0; r < 16; ++r) { accO[0][r] *= scl; accO[1][r] *= scl; }
            m = tmax;
        }

        // fused exp -> HW bf16 pack (v_cvt_pk_bf16_f32: 1 instr/pair)
        unsigned wv[16];
        float ls = 0.f;
#pragma unroll
        for (int a = 0; a < 8; ++a) {
            const float pa = fast_exp2(s0v[2 * a] - m);
            const float pb = fast_exp2(s0v[2 * a + 1] - m);
            ls += pa + pb;
            wv[a] = cvtpk_bf16(pa, pb);
        }
#pragma unroll
        for (int a = 0; a < 8; ++a) {
            const float pa = fast_exp2(s1v[2 * a] - m);
            const float pb = fast_exp2(s1v[2 * a + 1] - m);
            ls += pa + pb;
            wv[8 + a] = cvtpk_bf16(pa, pb);
        }
        ls += __shfl_xor(ls, 32);
        lsum += ls;

        // PV: per k-slot, B-frag via v_permlane32_swap (2 ops replace 4 shfl+4 sel)
#pragma unroll
        for (int slot2 = 0; slot2 < 4; ++slot2) {
            unsigned a0 = wv[slot2 * 4 + 0], a2 = wv[slot2 * 4 + 2];
            unsigned a1 = wv[slot2 * 4 + 1], a3 = wv[slot2 * 4 + 3];
            asm volatile("v_permlane32_swap_b32 %0, %1" : "+v"(a0), "+v"(a2));
            asm volatile("v_permlane32_swap_b32 %0, %1" : "+v"(a1), "+v"(a3));
            uint4 fr;
            fr.x = a0;   // == hi ? x2 : w0
            fr.y = a1;   // == hi ? x3 : w1
            fr.z = a2;   // == hi ? w2 : x0
            fr.w = a3;   // == hi ? w3 : x1
            const bf16x8 pfrag = __builtin_bit_cast(bf16x8, fr);
            __builtin_amdgcn_s_setprio(1);
#pragma unroll
            for (int db = 0; db < 2; ++db) {
                const int vr = 32 * db + l31;
                const int co = (16 * slot2 + 8 * hi) ^ ((vr & 7) << 3);
                const bf16x8 vf = *reinterpret_cast<const bf16x8*>(&Vb[vr * 64 + co]);
                accO[db] = __builtin_amdgcn_mfma_f32_32x32x16_bf16(vf, pfrag, accO[db], 0, 0, 0);
            }
            __builtin_amdgcn_s_setprio(0);
        }
    }

    // ---- flash merge of the two kv-split partials ----
    __syncthreads();                     // loop LDS use complete
    if (!hi) mlx[(wq2 * 2 + wkv) * 32 + l31] = make_float2(m, lsum);
    __syncthreads();
    const float2 mp = mlx[(wq2 * 2 + (1 - wkv)) * 32 + l31];
    const float M  = fmaxf(m, mp.x);
    const float s  = fast_exp2(m - M);
    const float lf = lsum * s + mp.y * fast_exp2(mp.x - M);

    if (wkv == 1) {                      // publish scaled partial (overlays Ks region)
#pragma unroll
        for (int db = 0; db < 2; ++db)
#pragma unroll
            for (int r = 0; r < 16; ++r) {
                const int d = 32 * db + (r & 3) + 8 * (r >> 2) + 4 * hi;
                xch[wq2 * 2048 + d * 32 + l31] = accO[db][r] * s;
            }
    }
    __syncthreads();
    if (wkv == 0) {                      // merge + normalize + Ep transpose
        const float inv = 1.f / lf;
#pragma unroll
        for (int db = 0; db < 2; ++db)
#pragma unroll
            for (int r = 0; r < 16; ++r) {
                const int d = 32 * db + (r & 3) + 8 * (r >> 2) + 4 * hi;
                accO[db][r] = (accO[db][r] * s + xch[wq2 * 2048 + d * 32 + l31]) * inv;
            }
#pragma unroll
        for (int db = 0; db < 2; ++db)
#pragma unroll
            for (int a = 0; a < 8; ++a) {
                const unsigned wd = packbf2(accO[db][2 * a], accO[db][2 * a + 1]);
                const int pi = 16 * db + 4 * (a >> 1) + (a & 1) + 2 * hi;  // d-pair index
                Ep[(wq2 * 32 + l31) * 33 + pi] = wd;
            }
    }
    __syncthreads();                     // fence Ep writes -> reads
    if (wkv == 0) {
#pragma unroll
        for (int pss = 0; pss < 4; ++pss) {
            const int idx = pss * 64 + l;
            const int qr = idx >> 3, c = idx & 7;
            uint4 ov;
            ov.x = Ep[(wq2 * 32 + qr) * 33 + c * 4 + 0];
            ov.y = Ep[(wq2 * 32 + qr) * 33 + c * 4 + 1];
            ov.z = Ep[(wq2 * 32 + qr) * 33 + c * 4 + 2];
            ov.w = Ep[(wq2 * 32 + qr) * 33 + c * 4 + 3];
            *reinterpret_cast<uint4*>(&O[((size_t)b * SEQ + q0 + wq2 * 32 + qr) * HIDDEN + h * HDIM + c * 8]) = ov;
        }
    }
}

// ---------------------------------------------------------------------------
extern "C" void kernel_launch(void* const* d_in, const int* in_sizes, int n_in,
                              void* d_out, int out_size, void* d_ws, size_t ws_size,
                              hipStream_t stream)
{
    const float* x  = (const float*)d_in[0];
    const float* Wq = (const float*)d_in[1];
    const float* bq = (const float*)d_in[2];
    const float* Wk = (const float*)d_in[3];
    const float* bk = (const float*)d_in[4];
    const float* Wv = (const float*)d_in[5];
    const float* bv = (const float*)d_in[6];
    const float* Wo = (const float*)d_in[7];
    const float* bo = (const float*)d_in[8];
    float* out = (float*)d_out;

    unsigned short* p = (unsigned short*)d_ws;
    const size_t szX = (size_t)NROWS * HIDDEN;
    const size_t szW = (size_t)HIDDEN * HIDDEN;
    const size_t szH = (size_t)BATCH * NHEADS * SEQ * HDIM;
    unsigned short* xb  = p;              p += szX;
    unsigned short* Wqt = p;              p += szW;
    unsigned short* Wkt = p;              p += szW;
    unsigned short* Wvt = p;              p += szW;
    unsigned short* Wot = p;              p += szW;
    unsigned short* Qb  = p;              p += szH;
    unsigned short* Kb  = p;              p += szH;
    unsigned short* Vtb = p;              p += szH;
    unsigned short* Oab = p;              p += szX;

    cvt_bf16<<<(int)(szX / 4 + 255) / 256, 256, 0, stream>>>(x, xb, (int)(szX / 4));
    transpose_cvt4<<<dim3(HIDDEN / 64, HIDDEN / 64, 4), 256, 0, stream>>>(
        Wq, Wk, Wv, Wo, Wqt, Wkt, Wvt, Wot);

    qkv_gemm<<<dim3(HIDDEN / 96, NROWS / 64, 3), 256, 0, stream>>>(
        xb, Wqt, Wkt, Wvt, bq, bk, bv, Qb, Kb, Vtb);

    attn_mfma<<<dim3(SEQ / 64, NHEADS, BATCH), 256, 0, stream>>>(Qb, Kb, Vtb, Oab);

    out_gemm<<<dim3(HIDDEN / 96, NROWS / 64), 256, 0, stream>>>(Oab, Wot, bo, out);
}